// Round 12
// baseline (556.921 us; speedup 1.0000x reference)
//
#include <hip/hip_runtime.h>
#include <math.h>

#define BB 2
#define CC 512
#define HH 30
#define WW 40
#define KK 64
#define NPIX (HH*WW)
#define HP 27
#define WP 37
#define NP (HP*WP)
#define LEPS 1e-12f

#define PADW 164      // xn ring row stride: 4*40 + 4 (164%32=4 -> <=2-way read banks)
#define SROW 484      // soft slab per k: 12 rows * 40 + 4 margin (j=39,dx=3 overrun)
#define NCG 8         // c-groups (64 c each)

// ---------------------------------------------------------------------------
// Kernel 1: per-(b,h) row: channel L2-norm, xn store, logits (K=64) + softmax.
// (proven since R1)
// ---------------------------------------------------------------------------
__global__ __launch_bounds__(512) void k_norm_soft(
    const float* __restrict__ x, const float* __restrict__ convw,
    float* __restrict__ xn, float* __restrict__ soft)
{
  const int h = blockIdx.x, b = blockIdx.y;
  const int t = threadIdx.x;
  __shared__ float xc[64][41];
  __shared__ float cw[64][65];
  __shared__ float Lb[KK][WW + 1];
  __shared__ float psum[12][WW];
  __shared__ float invn[WW];
  __shared__ float mx[WW], Zs[WW];

  const size_t xbase = (size_t)b * CC * NPIX + (size_t)h * WW;

  if (t < 480) {
    const int w = t % 40, part = t / 40;
    float s = 0.f;
    for (int c = part; c < CC; c += 12) {
      const float v = x[xbase + (size_t)c * NPIX + w];
      s = fmaf(v, v, s);
    }
    psum[part][w] = s;
  }
  __syncthreads();
  if (t < 40) {
    float s = 0.f;
    #pragma unroll
    for (int p = 0; p < 12; ++p) s += psum[p][t];
    invn[t] = 1.f / fmaxf(sqrtf(s), LEPS);
  }
  __syncthreads();

  const int k = t & 63, wp = t >> 6;
  float acc[5] = {0.f, 0.f, 0.f, 0.f, 0.f};
  for (int cb = 0; cb < CC; cb += 64) {
    #pragma unroll
    for (int n = 0; n < 5; ++n) {
      const int idx = t + 512 * n;
      const int c = idx / 40, w = idx % 40;
      const float v = x[xbase + (size_t)(cb + c) * NPIX + w] * invn[w];
      xc[c][w] = v;
      xn[xbase + (size_t)(cb + c) * NPIX + w] = v;
    }
    #pragma unroll
    for (int n = 0; n < 8; ++n) {
      const int idx = t + 512 * n;
      const int kk2 = idx >> 6, c2 = idx & 63;
      cw[kk2][c2] = convw[(size_t)kk2 * CC + cb + c2];
    }
    __syncthreads();
    #pragma unroll 1
    for (int c = 0; c < 64; ++c) {
      const float cv = cw[k][c];
      #pragma unroll
      for (int n = 0; n < 5; ++n)
        acc[n] = fmaf(cv, xc[c][wp + 8 * n], acc[n]);
    }
    __syncthreads();
  }
  #pragma unroll
  for (int n = 0; n < 5; ++n) Lb[k][wp + 8 * n] = acc[n];
  __syncthreads();
  if (t < 40) {
    float m = -1e30f;
    for (int kk2 = 0; kk2 < KK; ++kk2) m = fmaxf(m, Lb[kk2][t]);
    float Z = 0.f;
    for (int kk2 = 0; kk2 < KK; ++kk2) Z += expf(Lb[kk2][t] - m);
    mx[t] = m; Zs[t] = Z;
  }
  __syncthreads();
  const size_t sbase = (size_t)b * KK * NPIX + (size_t)h * WW;
  #pragma unroll
  for (int n = 0; n < 5; ++n) {
    const int idx = t + 512 * n;
    const int kk2 = idx / 40, w = idx % 40;
    soft[sbase + (size_t)kk2 * NPIX + w] = expf(Lb[kk2][w] - mx[w]) / Zs[w];
  }
}

// ---------------------------------------------------------------------------
// Kernel G: per-(b,k) global VLAD row, first L2 norm over c. (unchanged)
// ---------------------------------------------------------------------------
__global__ __launch_bounds__(256) void k_global(
    const float* __restrict__ xn, const float* __restrict__ soft,
    const float* __restrict__ cent, float* __restrict__ ghat)
{
  const int k = blockIdx.x, b = blockIdx.y, t = threadIdx.x;
  __shared__ float sb[NPIX];
  __shared__ float red[256];
  const float* srow = soft + ((size_t)b * KK + k) * NPIX;
  for (int i2 = t; i2 < NPIX; i2 += 256) sb[i2] = srow[i2];
  __syncthreads();
  float p = 0.f;
  for (int i2 = t; i2 < NPIX; i2 += 256) p += sb[i2];
  red[t] = p;
  __syncthreads();
  for (int s = 128; s > 0; s >>= 1) { if (t < s) red[t] += red[t + s]; __syncthreads(); }
  const float Sg = red[0];
  __syncthreads();

  const int c0 = t, c1 = t + 256;
  const float* x0 = xn + ((size_t)b * CC + c0) * NPIX;
  const float* x1 = xn + ((size_t)b * CC + c1) * NPIX;
  float a0 = 0.f, a1 = 0.f;
  for (int p4 = 0; p4 < NPIX; p4 += 4) {
    const float4 s4 = *(const float4*)&sb[p4];
    const float4 v0 = *(const float4*)(x0 + p4);
    const float4 v1 = *(const float4*)(x1 + p4);
    a0 = fmaf(s4.x, v0.x, a0); a0 = fmaf(s4.y, v0.y, a0);
    a0 = fmaf(s4.z, v0.z, a0); a0 = fmaf(s4.w, v0.w, a0);
    a1 = fmaf(s4.x, v1.x, a1); a1 = fmaf(s4.y, v1.y, a1);
    a1 = fmaf(s4.z, v1.z, a1); a1 = fmaf(s4.w, v1.w, a1);
  }
  const float g0 = a0 - cent[(size_t)k * CC + c0] * Sg;
  const float g1 = a1 - cent[(size_t)k * CC + c1] * Sg;
  red[t] = g0 * g0 + g1 * g1;
  __syncthreads();
  for (int s = 128; s > 0; s >>= 1) { if (t < s) red[t] += red[t + s]; __syncthreads(); }
  const float inv = 1.f / fmaxf(sqrtf(red[0]), LEPS);
  float* gr = ghat + ((size_t)b * KK + k) * CC;
  gr[c0] = g0 * inv; gr[c1] = g1 * inv;
}

// Global second norm: (a) per-b sum of squares -> inv scale, (b) wide scale.
__global__ __launch_bounds__(256) void k_g2a(
    const float* __restrict__ ghat, float* __restrict__ inv2g)
{
  const int b = blockIdx.x, t = threadIdx.x;
  __shared__ float red[256];
  const float* gb = ghat + (size_t)b * KK * CC;
  float p = 0.f;
  for (int i2 = t; i2 < KK * CC; i2 += 256) { const float v = gb[i2]; p = fmaf(v, v, p); }
  red[t] = p;
  __syncthreads();
  for (int s = 128; s > 0; s >>= 1) { if (t < s) red[t] += red[t + s]; __syncthreads(); }
  if (t == 0) inv2g[b] = 1.f / fmaxf(sqrtf(red[0]), LEPS);
}

__global__ __launch_bounds__(256) void k_g2b(
    const float* __restrict__ ghat, const float* __restrict__ inv2g,
    float* __restrict__ outg)
{
  const int b = blockIdx.y;
  const int u = blockIdx.x * 256 + threadIdx.x;
  if (u < KK * CC)
    outg[(size_t)b * KK * CC + u] = ghat[(size_t)b * KK * CC + u] * inv2g[b];
}

// ---------------------------------------------------------------------------
// Kernel L v10: R4's proven v5 body at 3 blocks/CU.
// Lane map c8 = t&7 (lane bits -> shfl_xor c-reduce), j = t>>3.
// xn ring [64][164] (read banks (4*c8+j)%32 <= 2-way = free), i-thirds
// (9 rows/block, soft slab 12 rows), no red buffer. LDS = 49.8 KB ->
// 3 blocks/CU = 15 waves. Ring discipline identical to R4 (reg prefetch,
// 2 barriers/iter). Grid 8x16x6 = 768 = 256 CU x 3: zero tail.
// PHASE 0: sp partials (shfl_xor over c8 octet).
// PHASE 1: raw * fs -> out (per-instr: 8 rows x 32B chunks; block's 5 waves
// fill each 64B line within the same iteration -> merges in L2).
// ---------------------------------------------------------------------------
template<int PHASE>
__global__ __launch_bounds__(320, 3) void k_local7(
    const float* __restrict__ xn, const float* __restrict__ soft,
    const float* __restrict__ cent, float* __restrict__ sp,
    const float* __restrict__ fs, float* __restrict__ out)
{
  const int cg = blockIdx.x;             // 0..7 (64 c)
  const int k0 = blockIdx.y * 4;         // k group
  const int bz = blockIdx.z;             // b*3 + iz
  const int b = bz / 3, iz = bz % 3;
  const int i0 = iz * 9;                 // 9 output rows per block
  const int c0 = cg * 64;
  const int t = threadIdx.x;
  const int c8 = t & 7, j = t >> 3;      // c8 in lane bits; j 0..39

  __shared__ float xn_l[64][PADW];       // 41984 B
  __shared__ float soft_l[4][SROW];      //  7744 B
  __shared__ float cent_l[4][64];        //  1024 B  -> 49.8 KB total

  // stage soft slab rows i0..i0+11 (120 float4 per k)
  for (int u = t; u < 480; u += 320) {
    const int kk = u / 120, q = u - (u / 120) * 120;
    *(float4*)&soft_l[kk][q * 4] =
      *(const float4*)&soft[((size_t)(b * KK + k0 + kk)) * NPIX + i0 * 40 + q * 4];
  }
  if (t < 256) cent_l[t >> 6][t & 63] = cent[(size_t)(k0 + (t >> 6)) * CC + c0 + (t & 63)];

  const int sc = t / 10, sq = t % 10;
  // prologue: stage xn rows i0..i0+3 into ring
  #pragma unroll
  for (int rr = 0; rr < 4; ++rr) {
    const int row = i0 + rr;
    const int slot = (row & 3) * 40 + sq * 4;
    *(float4*)&xn_l[sc][slot] =
      *(const float4*)&xn[((size_t)(b * CC + c0 + sc)) * NPIX + (size_t)row * 40 + sq * 4];
    *(float4*)&xn_l[sc + 32][slot] =
      *(const float4*)&xn[((size_t)(b * CC + c0 + sc + 32)) * NPIX + (size_t)row * 40 + sq * 4];
  }
  __syncthreads();

  for (int ii = 0; ii < 9; ++ii) {
    const int i = i0 + ii;

    // prefetch row i+4 into registers (ds-written after barrier 1)
    const int nrow = (i + 4 < HH) ? (i + 4) : (HH - 1);
    const float4 st0 = *(const float4*)&xn[((size_t)(b * CC + c0 + sc)) * NPIX
                                           + (size_t)nrow * 40 + sq * 4];
    const float4 st1 = *(const float4*)&xn[((size_t)(b * CC + c0 + sc + 32)) * NPIX
                                           + (size_t)nrow * 40 + sq * 4];
    float fsv[4];
    if (PHASE == 1) {
      #pragma unroll
      for (int kk = 0; kk < 4; ++kk)
        fsv[kk] = (j < WP)
          ? fs[((size_t)(b * KK + k0 + kk)) * NP + (size_t)i * WP + j] : 0.f;
    }

    // ---- compute (R4 v5 inner body; j>=37 lanes compute in-bounds garbage) ----
    float acc[8][4];
    float Ssum[4] = {0.f, 0.f, 0.f, 0.f};
    #pragma unroll
    for (int cc = 0; cc < 8; ++cc)
      #pragma unroll
      for (int kk = 0; kk < 4; ++kk) acc[cc][kk] = 0.f;
    #pragma unroll
    for (int r = 0; r < 4; ++r) {
      const int xo = ((i + r) & 3) * 40 + j;
      const int so = (ii + r) * 40 + j;
      float sv[4][4];
      #pragma unroll
      for (int kk = 0; kk < 4; ++kk) {
        #pragma unroll
        for (int dx = 0; dx < 4; ++dx) sv[kk][dx] = soft_l[kk][so + dx];
        Ssum[kk] += (sv[kk][0] + sv[kk][1]) + (sv[kk][2] + sv[kk][3]);
      }
      #pragma unroll
      for (int cc = 0; cc < 8; ++cc) {
        const float x0 = xn_l[cc * 8 + c8][xo + 0];
        const float x1 = xn_l[cc * 8 + c8][xo + 1];
        const float x2 = xn_l[cc * 8 + c8][xo + 2];
        const float x3 = xn_l[cc * 8 + c8][xo + 3];
        #pragma unroll
        for (int kk = 0; kk < 4; ++kk) {
          float a = acc[cc][kk];
          a = fmaf(x0, sv[kk][0], a);
          a = fmaf(x1, sv[kk][1], a);
          a = fmaf(x2, sv[kk][2], a);
          a = fmaf(x3, sv[kk][3], a);
          acc[cc][kk] = a;
        }
      }
    }

    // ---- epilogue ----
    if (PHASE == 0) {
      #pragma unroll
      for (int kk = 0; kk < 4; ++kk) {
        float s = 0.f;
        #pragma unroll
        for (int cc = 0; cc < 8; ++cc) {
          const float raw = fmaf(-cent_l[kk][cc * 8 + c8], Ssum[kk], acc[cc][kk]);
          s = fmaf(raw, raw, s);
        }
        s += __shfl_xor(s, 1, 64);
        s += __shfl_xor(s, 2, 64);
        s += __shfl_xor(s, 4, 64);
        if (c8 == 0 && j < WP)
          sp[(((size_t)(b * KK + k0 + kk)) * NCG + cg) * NP + (size_t)i * WP + j] = s;
      }
    } else if (j < WP) {
      #pragma unroll
      for (int kk = 0; kk < 4; ++kk) {
        #pragma unroll
        for (int cc = 0; cc < 8; ++cc) {
          const float raw = fmaf(-cent_l[kk][cc * 8 + c8], Ssum[kk], acc[cc][kk]);
          out[((size_t)((b * KK + k0 + kk) * CC + c0 + cc * 8 + c8)) * NP
              + (size_t)i * WP + j] = raw * fsv[kk];
        }
      }
    }
    __syncthreads();   // barrier 1: ring slot i&3 free

    // write prefetched row into slot (i+4)&3 (== i&3)
    {
      const int slot = ((i + 4) & 3) * 40 + sq * 4;
      *(float4*)&xn_l[sc][slot] = st0;
      *(float4*)&xn_l[sc + 32][slot] = st1;
    }
    __syncthreads();   // barrier 2: new row visible
  }
}

// ---------------------------------------------------------------------------
// Kernel NF: per (b, 4 pixels): sum the 8 c-group partials, build the exact
// per-(b,k,p) scale with a 64-way LDS reduce for the cross-k second norm.
// ---------------------------------------------------------------------------
__global__ __launch_bounds__(256) void k_nf(
    const float* __restrict__ sp, float* __restrict__ fs)
{
  const int b = blockIdx.y, t = threadIdx.x;
  const int k = t >> 2, dp = t & 3;
  const int p = blockIdx.x * 4 + dp;
  __shared__ float red[64][4];
  __shared__ float inv2s[4];
  const bool ok = p < NP;
  float sr = 0.f;
  if (ok) {
    #pragma unroll
    for (int g = 0; g < NCG; ++g)
      sr += sp[(((size_t)(b * KK + k)) * NCG + g) * NP + p];
  }
  const float iv = 1.f / fmaxf(sqrtf(sr) * 0.0625f, LEPS);
  red[k][dp] = sr * (1.f / 256.f) * iv * iv;
  __syncthreads();
  if (t < 4) {
    float s = 0.f;
    #pragma unroll
    for (int kk = 0; kk < 64; ++kk) s += red[kk][t];
    inv2s[t] = 1.f / fmaxf(sqrtf(s), LEPS);
  }
  __syncthreads();
  if (ok)
    fs[((size_t)(b * KK + k)) * NP + p] = 0.0625f * iv * inv2s[dp];
}

// ---------------------------------------------------------------------------
extern "C" void kernel_launch(void* const* d_in, const int* in_sizes, int n_in,
                              void* d_out, int out_size, void* d_ws, size_t ws_size,
                              hipStream_t stream)
{
  const float* x     = (const float*)d_in[0];
  const float* convw = (const float*)d_in[1];
  const float* cent  = (const float*)d_in[2];
  float* out = (float*)d_out;
  float* ws  = (float*)d_ws;

  float* xn    = ws;                                  // B*C*NPIX
  float* soft  = xn    + (size_t)BB * CC * NPIX;      // B*K*NPIX
  float* fs    = soft  + (size_t)BB * KK * NPIX;      // B*K*NP
  float* ghat  = fs    + (size_t)BB * KK * NP;        // B*K*C
  float* sp    = ghat  + (size_t)BB * KK * CC;        // B*K*NCG*NP
  float* inv2g = sp    + (size_t)BB * KK * NCG * NP;  // B

  float* outg = out + (size_t)BB * KK * CC * NP;

  k_norm_soft<<<dim3(HH, BB), 512, 0, stream>>>(x, convw, xn, soft);
  k_local7<0><<<dim3(NCG, KK / 4, BB * 3), 320, 0, stream>>>(xn, soft, cent, sp, fs, out);
  k_global<<<dim3(KK, BB), 256, 0, stream>>>(xn, soft, cent, ghat);
  k_g2a<<<dim3(BB), 256, 0, stream>>>(ghat, inv2g);
  k_g2b<<<dim3((KK * CC + 255) / 256, BB), 256, 0, stream>>>(ghat, inv2g, outg);
  k_nf<<<dim3((NP + 3) / 4, BB), 256, 0, stream>>>(sp, fs);
  k_local7<1><<<dim3(NCG, KK / 4, BB * 3), 320, 0, stream>>>(xn, soft, cent, sp, fs, out);
}